// Round 1
// baseline (517.974 us; speedup 1.0000x reference)
//
#include <hip/hip_runtime.h>
#include <cstddef>

#define WIN 11
#define HALO 10
#define NCH 10

// Normalized 1D Gaussian, sigma=1.5, 11 taps (computed to ~1e-8).
__device__ __constant__ float G[WIN] = {
    0.00102838f, 0.00759876f, 0.03600077f, 0.10936069f, 0.21300554f,
    0.26601173f, 0.21300554f, 0.10936069f, 0.03600077f, 0.00759876f,
    0.00102838f};

constexpr int TX = 32;
constexpr int TY = 32;
constexpr int IN_W = TX + HALO;     // 42
constexpr int IN_H = TY + HALO;     // 42
constexpr int IN_PITCH = IN_W + 2;  // 44 (bank-conflict-friendly pad)
constexpr int HT = IN_H * TX;       // 1344

__global__ void zero_acc(float* acc) { acc[threadIdx.x] = 0.f; }

__global__ __launch_bounds__(256) void pool2(const float* __restrict__ src,
                                             float* __restrict__ dst,
                                             int Hs, int Ws) {
    const int Hd = Hs >> 1, Wd = Ws >> 1;
    int idx = blockIdx.x * 256 + threadIdx.x;
    int total = NCH * Hd * Wd;
    if (idx >= total) return;
    int x = idx % Wd;
    int r = idx / Wd;
    int y = r % Hd;
    int c = r / Hd;
    const float2* r0 = (const float2*)(src + ((size_t)c * Hs + 2 * y) * Ws);
    const float2* r1 = (const float2*)(src + ((size_t)c * Hs + 2 * y + 1) * Ws);
    float2 a = r0[x];
    float2 b = r1[x];
    dst[idx] = 0.25f * ((a.x + a.y) + (b.x + b.y));
}

__global__ __launch_bounds__(256) void ssim_level(const float* __restrict__ P,
                                                  const float* __restrict__ T,
                                                  float* __restrict__ acc,
                                                  int H, int W, int lvl) {
    __shared__ float sp[IN_H * IN_PITCH];
    __shared__ float st[IN_H * IN_PITCH];
    __shared__ float hbuf[5 * HT];  // h[q][y][x], x-size 32
    __shared__ float red[8];

    const int c = blockIdx.z;
    const int Hout = H - HALO, Wout = W - HALO;
    const int ox0 = blockIdx.x * TX;
    const int oy0 = blockIdx.y * TY;
    const float* Pc = P + (size_t)c * H * W;
    const float* Tc = T + (size_t)c * H * W;
    const int tid = threadIdx.x;

    // Stage 0: global -> LDS (halo tile, zero-fill OOB; OOB outputs are discarded)
    for (int i = tid; i < IN_H * IN_W; i += 256) {
        int y = i / IN_W;
        int x = i - y * IN_W;
        int gy = oy0 + y, gx = ox0 + x;
        float pv = 0.f, tv = 0.f;
        if (gy < H && gx < W) {
            size_t o = (size_t)gy * W + gx;
            pv = Pc[o];
            tv = Tc[o];
        }
        sp[y * IN_PITCH + x] = pv;
        st[y * IN_PITCH + x] = tv;
    }
    __syncthreads();

    // Stage 1: horizontal conv of 5 quantities (products formed on the fly)
    for (int i = tid; i < HT; i += 256) {
        int y = i >> 5;
        int x = i & (TX - 1);
        const float* rp = sp + y * IN_PITCH + x;
        const float* rt = st + y * IN_PITCH + x;
        float s1 = 0.f, s2 = 0.f, s11 = 0.f, s22 = 0.f, s12 = 0.f;
#pragma unroll
        for (int k = 0; k < WIN; ++k) {
            float g = G[k];
            float pv = rp[k];
            float tv = rt[k];
            s1 = fmaf(g, pv, s1);
            s2 = fmaf(g, tv, s2);
            s11 = fmaf(g, pv * pv, s11);
            s22 = fmaf(g, tv * tv, s22);
            s12 = fmaf(g, pv * tv, s12);
        }
        hbuf[0 * HT + i] = s1;
        hbuf[1 * HT + i] = s2;
        hbuf[2 * HT + i] = s11;
        hbuf[3 * HT + i] = s22;
        hbuf[4 * HT + i] = s12;
    }
    __syncthreads();

    // Stage 2: vertical conv + per-pixel SSIM/CS, 4 output rows per thread
    float cs_sum = 0.f, sim_sum = 0.f;
    const int tx = tid & (TX - 1);
    const int ty0 = tid >> 5;
#pragma unroll
    for (int j = 0; j < 4; ++j) {
        const int oy = ty0 + j * 8;
        float m1 = 0.f, m2 = 0.f, q11 = 0.f, q22 = 0.f, q12 = 0.f;
#pragma unroll
        for (int k = 0; k < WIN; ++k) {
            int row = (oy + k) * TX + tx;
            float g = G[k];
            m1 = fmaf(g, hbuf[0 * HT + row], m1);
            m2 = fmaf(g, hbuf[1 * HT + row], m2);
            q11 = fmaf(g, hbuf[2 * HT + row], q11);
            q22 = fmaf(g, hbuf[3 * HT + row], q22);
            q12 = fmaf(g, hbuf[4 * HT + row], q12);
        }
        if (ox0 + tx < Wout && oy0 + oy < Hout) {
            const float C1c = 1.0e-4f, C2c = 9.0e-4f;
            float mu1s = m1 * m1, mu2s = m2 * m2, mu12 = m1 * m2;
            float sig1 = q11 - mu1s;
            float sig2 = q22 - mu2s;
            float sig12 = q12 - mu12;
            float v1 = 2.f * sig12 + C2c;
            float v2 = sig1 + sig2 + C2c;
            cs_sum += v1 / v2;
            sim_sum += ((2.f * mu12 + C1c) * v1) / ((mu1s + mu2s + C1c) * v2);
        }
    }

    // Block reduction: wave64 shuffle, then cross-wave via LDS
#pragma unroll
    for (int off = 32; off > 0; off >>= 1) {
        cs_sum += __shfl_down(cs_sum, off, 64);
        sim_sum += __shfl_down(sim_sum, off, 64);
    }
    int wave = tid >> 6;
    if ((tid & 63) == 0) {
        red[wave * 2 + 0] = sim_sum;
        red[wave * 2 + 1] = cs_sum;
    }
    __syncthreads();
    if (tid == 0) {
        float s = red[0] + red[2] + red[4] + red[6];
        float cc = red[1] + red[3] + red[5] + red[7];
        atomicAdd(&acc[(lvl * NCH + c) * 2 + 0], s);
        atomicAdd(&acc[(lvl * NCH + c) * 2 + 1], cc);
    }
}

__global__ void finalize_k(const float* __restrict__ acc, float* __restrict__ out) {
    if (threadIdx.x != 0) return;
    const double w[5] = {0.0448, 0.2856, 0.3001, 0.2363, 0.1333};
    const double counts[5] = {1014.0 * 1014.0, 502.0 * 502.0, 246.0 * 246.0,
                              118.0 * 118.0, 54.0 * 54.0};
    double total = 0.0;
    for (int c = 0; c < NCH; ++c) {
        double pc = 1.0;
        for (int l = 0; l < 4; ++l) {
            double mcs = (double)acc[(l * NCH + c) * 2 + 1] / counts[l];
            pc *= pow(mcs, w[l]);
        }
        double ms4 = (double)acc[(4 * NCH + c) * 2 + 0] / counts[4];
        double p2 = pow(ms4, w[4]);
        pc *= (p2 * p2) * (p2 * p2);   // pow2[-1] enters the product 4x
        total += pc;
    }
    *out = (float)(1.0 - total);
}

extern "C" void kernel_launch(void* const* d_in, const int* in_sizes, int n_in,
                              void* d_out, int out_size, void* d_ws, size_t ws_size,
                              hipStream_t stream) {
    const float* P0 = (const float*)d_in[0];
    const float* T0 = (const float*)d_in[1];
    float* out = (float*)d_out;
    float* acc = (float*)d_ws;  // 100 used, 128 reserved

    const size_t n1 = (size_t)NCH * 512 * 512;
    const size_t n2 = (size_t)NCH * 256 * 256;
    const size_t n3 = (size_t)NCH * 128 * 128;
    const size_t n4 = (size_t)NCH * 64 * 64;
    float* p1 = acc + 128;
    float* t1 = p1 + n1;
    float* p2 = t1 + n1;
    float* t2 = p2 + n2;
    float* p3 = t2 + n2;
    float* t3 = p3 + n3;
    float* p4 = t3 + n3;
    float* t4 = p4 + n4;

    zero_acc<<<1, 128, 0, stream>>>(acc);

    pool2<<<(int)((n1 + 255) / 256), 256, 0, stream>>>(P0, p1, 1024, 1024);
    pool2<<<(int)((n1 + 255) / 256), 256, 0, stream>>>(T0, t1, 1024, 1024);
    pool2<<<(int)((n2 + 255) / 256), 256, 0, stream>>>(p1, p2, 512, 512);
    pool2<<<(int)((n2 + 255) / 256), 256, 0, stream>>>(t1, t2, 512, 512);
    pool2<<<(int)((n3 + 255) / 256), 256, 0, stream>>>(p2, p3, 256, 256);
    pool2<<<(int)((n3 + 255) / 256), 256, 0, stream>>>(t2, t3, 256, 256);
    pool2<<<(int)((n4 + 255) / 256), 256, 0, stream>>>(p3, p4, 128, 128);
    pool2<<<(int)((n4 + 255) / 256), 256, 0, stream>>>(t3, t4, 128, 128);

    auto launch_level = [&](const float* P, const float* T, int H, int lvl) {
        int Hout = H - HALO;
        dim3 grid((Hout + TX - 1) / TX, (Hout + TY - 1) / TY, NCH);
        ssim_level<<<grid, 256, 0, stream>>>(P, T, acc, H, H, lvl);
    };
    launch_level(P0, T0, 1024, 0);
    launch_level(p1, t1, 512, 1);
    launch_level(p2, t2, 256, 2);
    launch_level(p3, t3, 128, 3);
    launch_level(p4, t4, 64, 4);

    finalize_k<<<1, 64, 0, stream>>>(acc, out);
}

// Round 2
// 481.196 us; speedup vs baseline: 1.0764x; 1.0764x over previous
//
#include <hip/hip_runtime.h>
#include <cstddef>

#define WIN 11
#define HALO 10
#define NCH 10

// Normalized 1D Gaussian, sigma=1.5 (constexpr so unrolled taps fold to immediates)
constexpr float Gc[WIN] = {
    0.00102838f, 0.00759876f, 0.03600077f, 0.10936069f, 0.21300554f,
    0.26601173f, 0.21300554f, 0.10936069f, 0.03600077f, 0.00759876f,
    0.00102838f};

constexpr int TX = 32;
constexpr int TY = 32;
constexpr int IN_W = TX + HALO;        // 42
constexpr int IN_H = TY + HALO;        // 42
constexpr int PITCH = 44;              // even pitch: float2 LDS writes stay 8B-aligned
constexpr int SPSZ = IN_H * PITCH + 16; // +16 tail: stage-1 reads overrun by <=4
constexpr int HROW = TX;
constexpr int HSZ = IN_H * HROW;       // 1344

__global__ void zero_acc(float* acc) { acc[threadIdx.x] = 0.f; }

// Fused p+t 2x2 average pool (square images)
__global__ __launch_bounds__(256) void pool2x2(const float* __restrict__ sp_,
                                               const float* __restrict__ st_,
                                               float* __restrict__ dp,
                                               float* __restrict__ dt, int Hs) {
    const int Ws = Hs;
    const int Hd = Hs >> 1, Wd = Ws >> 1;
    int idx = blockIdx.x * 256 + threadIdx.x;
    int total = NCH * Hd * Wd;
    if (idx >= total) return;
    int x = idx % Wd;
    int r = idx / Wd;
    int y = r % Hd;
    int ch = r / Hd;
    size_t o0 = ((size_t)ch * Hs + 2 * y) * Ws;
    const float2* pr0 = (const float2*)(sp_ + o0);
    const float2* pr1 = (const float2*)(sp_ + o0 + Ws);
    float2 a = pr0[x], b = pr1[x];
    dp[idx] = 0.25f * ((a.x + a.y) + (b.x + b.y));
    const float2* tr0 = (const float2*)(st_ + o0);
    const float2* tr1 = (const float2*)(st_ + o0 + Ws);
    float2 ta = tr0[x], tb = tr1[x];
    dt[idx] = 0.25f * ((ta.x + ta.y) + (tb.x + tb.y));
}

__global__ __launch_bounds__(256) void ssim_level(const float* __restrict__ P,
                                                  const float* __restrict__ T,
                                                  float* __restrict__ acc,
                                                  int H, int lvl) {
    __shared__ float sp[SPSZ];
    __shared__ float st[SPSZ];
    __shared__ float hbuf[5 * HSZ];
    __shared__ float red[8];

    const int W = H;
    const int c = blockIdx.z;
    const int Hout = H - HALO;  // == Wout (square)
    const int ox0 = blockIdx.x * TX;
    const int oy0 = blockIdx.y * TY;
    const float* Pc = P + (size_t)c * H * W;
    const float* Tc = T + (size_t)c * H * W;
    const int tid = threadIdx.x;

    // ---- Stage 0: global -> LDS, float2 vector loads (ox0 even, W even) ----
    for (int i = tid; i < IN_H * 21; i += 256) {
        int y = i / 21;
        int xp = (i - y * 21) * 2;
        int gy = oy0 + y, gx = ox0 + xp;
        float2 pv = make_float2(0.f, 0.f), tv = make_float2(0.f, 0.f);
        if (gy < H) {
            size_t o = (size_t)gy * W + gx;
            if (gx + 2 <= W) {
                pv = *(const float2*)(Pc + o);
                tv = *(const float2*)(Tc + o);
            } else if (gx < W) {
                pv.x = Pc[o];
                tv.x = Tc[o];
            }
        }
        *(float2*)(sp + y * PITCH + xp) = pv;
        *(float2*)(st + y * PITCH + xp) = tv;
    }
    __syncthreads();

    // ---- Stage 1: horizontal conv, streaming accumulators ----
    // 252 threads: 42 rows x 6 segments; each produces 6 consecutive x-outputs
    // from 16 streamed input columns -> 32 LDS reads for 6 h-pixels (vs 22/pixel).
    if (tid < 252) {
        const int r = tid / 6;
        const int seg = tid - r * 6;
        const int x0 = seg * 6;
        const float* rp = sp + r * PITCH + x0;
        const float* rt = st + r * PITCH + x0;
        float a0[6] = {}, a1[6] = {}, a2[6] = {}, a3[6] = {}, a4[6] = {};
#pragma unroll
        for (int xi = 0; xi < 16; ++xi) {
            float pv = rp[xi], tv = rt[xi];
            float pp = pv * pv, tt = tv * tv, pt = pv * tv;
#pragma unroll
            for (int o = 0; o < 6; ++o) {
                int k = xi - o;
                if (k >= 0 && k <= 10) {
                    float g = Gc[k];
                    a0[o] = fmaf(g, pv, a0[o]);
                    a1[o] = fmaf(g, tv, a1[o]);
                    a2[o] = fmaf(g, pp, a2[o]);
                    a3[o] = fmaf(g, tt, a3[o]);
                    a4[o] = fmaf(g, pt, a4[o]);
                }
            }
        }
#pragma unroll
        for (int o = 0; o < 6; ++o) {
            int x = x0 + o;
            if (x < TX) {
                int idx = r * HROW + x;
                hbuf[0 * HSZ + idx] = a0[o];
                hbuf[1 * HSZ + idx] = a1[o];
                hbuf[2 * HSZ + idx] = a2[o];
                hbuf[3 * HSZ + idx] = a3[o];
                hbuf[4 * HSZ + idx] = a4[o];
            }
        }
    }
    __syncthreads();

    // ---- Stage 2: vertical conv, streaming accumulators ----
    // Each thread: column txl, 4 consecutive y-outputs from 14 streamed rows
    // -> 70 LDS reads for 4 outputs (vs 55/output).
    float cs_sum = 0.f, sim_sum = 0.f;
    {
        const int txl = tid & 31;
        const int g = tid >> 5;
        const int y0 = g * 4;
        float m1[4] = {}, m2[4] = {}, q11[4] = {}, q22[4] = {}, q12[4] = {};
#pragma unroll
        for (int yr = 0; yr < 14; ++yr) {
            int row = (y0 + yr) * HROW + txl;
            float h0 = hbuf[0 * HSZ + row];
            float h1 = hbuf[1 * HSZ + row];
            float h2 = hbuf[2 * HSZ + row];
            float h3 = hbuf[3 * HSZ + row];
            float h4 = hbuf[4 * HSZ + row];
#pragma unroll
            for (int o = 0; o < 4; ++o) {
                int k = yr - o;
                if (k >= 0 && k <= 10) {
                    float gw = Gc[k];
                    m1[o] = fmaf(gw, h0, m1[o]);
                    m2[o] = fmaf(gw, h1, m2[o]);
                    q11[o] = fmaf(gw, h2, q11[o]);
                    q22[o] = fmaf(gw, h3, q22[o]);
                    q12[o] = fmaf(gw, h4, q12[o]);
                }
            }
        }
        const float C1c = 1.0e-4f, C2c = 9.0e-4f;
#pragma unroll
        for (int o = 0; o < 4; ++o) {
            if (ox0 + txl < Hout && oy0 + y0 + o < Hout) {
                float mu1s = m1[o] * m1[o], mu2s = m2[o] * m2[o];
                float mu12 = m1[o] * m2[o];
                float sig1 = q11[o] - mu1s;
                float sig2 = q22[o] - mu2s;
                float sig12 = q12[o] - mu12;
                float v1 = 2.f * sig12 + C2c;
                float v2 = sig1 + sig2 + C2c;
                cs_sum += v1 / v2;
                sim_sum += ((2.f * mu12 + C1c) * v1) / ((mu1s + mu2s + C1c) * v2);
            }
        }
    }

    // ---- Block reduction ----
#pragma unroll
    for (int off = 32; off > 0; off >>= 1) {
        cs_sum += __shfl_down(cs_sum, off, 64);
        sim_sum += __shfl_down(sim_sum, off, 64);
    }
    int wave = tid >> 6;
    if ((tid & 63) == 0) {
        red[wave * 2 + 0] = sim_sum;
        red[wave * 2 + 1] = cs_sum;
    }
    __syncthreads();
    if (tid == 0) {
        float s = red[0] + red[2] + red[4] + red[6];
        float cc = red[1] + red[3] + red[5] + red[7];
        atomicAdd(&acc[(lvl * NCH + c) * 2 + 0], s);
        atomicAdd(&acc[(lvl * NCH + c) * 2 + 1], cc);
    }
}

__global__ void finalize_k(const float* __restrict__ acc, float* __restrict__ out) {
    if (threadIdx.x != 0) return;
    const double w[5] = {0.0448, 0.2856, 0.3001, 0.2363, 0.1333};
    const double counts[5] = {1014.0 * 1014.0, 502.0 * 502.0, 246.0 * 246.0,
                              118.0 * 118.0, 54.0 * 54.0};
    double total = 0.0;
    for (int c = 0; c < NCH; ++c) {
        double pc = 1.0;
        for (int l = 0; l < 4; ++l) {
            double mcs = (double)acc[(l * NCH + c) * 2 + 1] / counts[l];
            pc *= pow(mcs, w[l]);
        }
        double ms4 = (double)acc[(4 * NCH + c) * 2 + 0] / counts[4];
        double p2 = pow(ms4, w[4]);
        pc *= (p2 * p2) * (p2 * p2);  // pow2[-1] appears in all 4 product terms
        total += pc;
    }
    *out = (float)(1.0 - total);
}

extern "C" void kernel_launch(void* const* d_in, const int* in_sizes, int n_in,
                              void* d_out, int out_size, void* d_ws, size_t ws_size,
                              hipStream_t stream) {
    const float* P0 = (const float*)d_in[0];
    const float* T0 = (const float*)d_in[1];
    float* out = (float*)d_out;
    float* acc = (float*)d_ws;  // 100 used, 128 reserved

    const size_t n1 = (size_t)NCH * 512 * 512;
    const size_t n2 = (size_t)NCH * 256 * 256;
    const size_t n3 = (size_t)NCH * 128 * 128;
    const size_t n4 = (size_t)NCH * 64 * 64;
    float* p1 = acc + 128;
    float* t1 = p1 + n1;
    float* p2 = t1 + n1;
    float* t2 = p2 + n2;
    float* p3 = t2 + n2;
    float* t3 = p3 + n3;
    float* p4 = t3 + n3;
    float* t4 = p4 + n4;

    zero_acc<<<1, 128, 0, stream>>>(acc);

    pool2x2<<<(int)((n1 + 255) / 256), 256, 0, stream>>>(P0, T0, p1, t1, 1024);
    pool2x2<<<(int)((n2 + 255) / 256), 256, 0, stream>>>(p1, t1, p2, t2, 512);
    pool2x2<<<(int)((n3 + 255) / 256), 256, 0, stream>>>(p2, t2, p3, t3, 256);
    pool2x2<<<(int)((n4 + 255) / 256), 256, 0, stream>>>(p3, t3, p4, t4, 128);

    auto launch_level = [&](const float* P, const float* T, int H, int lvl) {
        int Hout = H - HALO;
        dim3 grid((Hout + TX - 1) / TX, (Hout + TY - 1) / TY, NCH);
        ssim_level<<<grid, 256, 0, stream>>>(P, T, acc, H, lvl);
    };
    launch_level(P0, T0, 1024, 0);
    launch_level(p1, t1, 512, 1);
    launch_level(p2, t2, 256, 2);
    launch_level(p3, t3, 128, 3);
    launch_level(p4, t4, 64, 4);

    finalize_k<<<1, 64, 0, stream>>>(acc, out);
}

// Round 3
// 396.978 us; speedup vs baseline: 1.3048x; 1.2121x over previous
//
#include <hip/hip_runtime.h>
#include <cstddef>

#define WIN 11
#define HALO 10
#define NCH 10

// Normalized 1D Gaussian, sigma=1.5 (constexpr: unrolled taps fold to immediates)
constexpr float Gc[WIN] = {
    0.00102838f, 0.00759876f, 0.03600077f, 0.10936069f, 0.21300554f,
    0.26601173f, 0.21300554f, 0.10936069f, 0.03600077f, 0.00759876f,
    0.00102838f};

constexpr int TX = 32;
constexpr int TY = 32;
constexpr int IN_H = TY + HALO;   // 42 h-rows per tile
constexpr int HPITCH = 33;        // pitch 33: stage-1 write bank=(r+x)%32 -> spread
constexpr int HSZ = IN_H * HPITCH;  // 1386

struct Ptrs {
    const float* p[5];
    const float* t[5];
};

__global__ void zero_acc(float* acc) { acc[threadIdx.x] = 0.f; }

// Fused p+t 2x2 average pool (square images)
__global__ __launch_bounds__(256) void pool2x2(const float* __restrict__ sp_,
                                               const float* __restrict__ st_,
                                               float* __restrict__ dp,
                                               float* __restrict__ dt, int Hs) {
    const int Ws = Hs;
    const int Hd = Hs >> 1, Wd = Ws >> 1;
    int idx = blockIdx.x * 256 + threadIdx.x;
    int total = NCH * Hd * Wd;
    if (idx >= total) return;
    int x = idx % Wd;
    int r = idx / Wd;
    int y = r % Hd;
    int ch = r / Hd;
    size_t o0 = ((size_t)ch * Hs + 2 * y) * Ws;
    const float2* pr0 = (const float2*)(sp_ + o0);
    const float2* pr1 = (const float2*)(sp_ + o0 + Ws);
    float2 a = pr0[x], b = pr1[x];
    dp[idx] = 0.25f * ((a.x + a.y) + (b.x + b.y));
    const float2* tr0 = (const float2*)(st_ + o0);
    const float2* tr1 = (const float2*)(st_ + o0 + Ws);
    float2 ta = tr0[x], tb = tr1[x];
    dt[idx] = 0.25f * ((ta.x + ta.y) + (tb.x + tb.y));
}

// All 5 MS-SSIM levels in ONE dispatch. blockIdx.x encodes (level, tile);
// blockIdx.y = channel. Per-level xy-tile counts: 1024/256/64/16/4 -> 1364.
__global__ __launch_bounds__(256, 5) void ssim_all(Ptrs ptrs,
                                                   float* __restrict__ acc) {
    __shared__ float hbuf[5 * HSZ];  // 27.1 KB -> 5 blocks/CU
    __shared__ float red[8];

    // ---- Level decode ----
    const int bx = blockIdx.x;
    int lvl, base;
    if (bx < 1024)      { lvl = 0; base = 0; }
    else if (bx < 1280) { lvl = 1; base = 1024; }
    else if (bx < 1344) { lvl = 2; base = 1280; }
    else if (bx < 1360) { lvl = 3; base = 1344; }
    else                { lvl = 4; base = 1360; }
    const int local = bx - base;
    const int tw = 32 >> lvl;            // tiles per row: 32/16/8/4/2
    const int txb = local & (tw - 1);
    const int tyb = local >> (5 - lvl);
    const int H = 1024 >> lvl;
    const int Hout = H - HALO;
    const int ox0 = txb * TX;
    const int oy0 = tyb * TY;
    const int c = blockIdx.y;
    const float* Pc = ptrs.p[lvl] + (size_t)c * H * H;
    const float* Tc = ptrs.t[lvl] + (size_t)c * H * H;
    const int tid = threadIdx.x;

    // ---- Stage 1: horizontal conv straight from global (no input staging) ----
    // 252 threads: 42 rows x 6 segments; each produces 6 consecutive h-outputs
    // from a 16-float window (float2 global loads, L1/L2-served overlap).
    if (tid < 252) {
        const int r = tid / 6;
        const int seg = tid - r * 6;
        const int x0 = seg * 6;
        const int gy = oy0 + r;
        const int gxb = ox0 + x0;
        const float* Pr = Pc + (size_t)gy * H + gxb;
        const float* Tr = Tc + (size_t)gy * H + gxb;
        float pw[16], twn[16];
        if (gy < H && gxb + 16 <= H) {  // fast path (all but edge tiles)
#pragma unroll
            for (int j = 0; j < 8; ++j) {
                float2 pv = *(const float2*)(Pr + 2 * j);
                float2 tv = *(const float2*)(Tr + 2 * j);
                pw[2 * j] = pv.x; pw[2 * j + 1] = pv.y;
                twn[2 * j] = tv.x; twn[2 * j + 1] = tv.y;
            }
        } else {
#pragma unroll
            for (int j = 0; j < 16; ++j) {
                bool ok = (gy < H) && (gxb + j < H);
                pw[j] = ok ? Pr[j] : 0.f;
                twn[j] = ok ? Tr[j] : 0.f;
            }
        }
        float a0[6] = {}, a1[6] = {}, a2[6] = {}, a3[6] = {}, a4[6] = {};
#pragma unroll
        for (int xi = 0; xi < 16; ++xi) {
            float pv = pw[xi], tv = twn[xi];
            float pp = pv * pv, tt = tv * tv, pt = pv * tv;
#pragma unroll
            for (int o = 0; o < 6; ++o) {
                int k = xi - o;
                if (k >= 0 && k <= 10) {
                    float g = Gc[k];
                    a0[o] = fmaf(g, pv, a0[o]);
                    a1[o] = fmaf(g, tv, a1[o]);
                    a2[o] = fmaf(g, pp, a2[o]);
                    a3[o] = fmaf(g, tt, a3[o]);
                    a4[o] = fmaf(g, pt, a4[o]);
                }
            }
        }
#pragma unroll
        for (int o = 0; o < 6; ++o) {
            int x = x0 + o;
            if (x < TX) {
                int idx = r * HPITCH + x;
                hbuf[0 * HSZ + idx] = a0[o];
                hbuf[1 * HSZ + idx] = a1[o];
                hbuf[2 * HSZ + idx] = a2[o];
                hbuf[3 * HSZ + idx] = a3[o];
                hbuf[4 * HSZ + idx] = a4[o];
            }
        }
    }
    __syncthreads();

    // ---- Stage 2: vertical conv, streaming accumulators, 4 outputs/thread ----
    float cs_sum = 0.f, sim_sum = 0.f;
    {
        const int txl = tid & 31;
        const int y0 = (tid >> 5) * 4;
        float m1[4] = {}, m2[4] = {}, q11[4] = {}, q22[4] = {}, q12[4] = {};
#pragma unroll
        for (int yr = 0; yr < 14; ++yr) {
            int row = (y0 + yr) * HPITCH + txl;
            float h0 = hbuf[0 * HSZ + row];
            float h1 = hbuf[1 * HSZ + row];
            float h2 = hbuf[2 * HSZ + row];
            float h3 = hbuf[3 * HSZ + row];
            float h4 = hbuf[4 * HSZ + row];
#pragma unroll
            for (int o = 0; o < 4; ++o) {
                int k = yr - o;
                if (k >= 0 && k <= 10) {
                    float gw = Gc[k];
                    m1[o] = fmaf(gw, h0, m1[o]);
                    m2[o] = fmaf(gw, h1, m2[o]);
                    q11[o] = fmaf(gw, h2, q11[o]);
                    q22[o] = fmaf(gw, h3, q22[o]);
                    q12[o] = fmaf(gw, h4, q12[o]);
                }
            }
        }
        const float C1c = 1.0e-4f, C2c = 9.0e-4f;
#pragma unroll
        for (int o = 0; o < 4; ++o) {
            if (ox0 + txl < Hout && oy0 + y0 + o < Hout) {
                float mu1s = m1[o] * m1[o], mu2s = m2[o] * m2[o];
                float mu12 = m1[o] * m2[o];
                float sig1 = q11[o] - mu1s;
                float sig2 = q22[o] - mu2s;
                float sig12 = q12[o] - mu12;
                float v1 = 2.f * sig12 + C2c;
                float v2 = sig1 + sig2 + C2c;
                cs_sum += v1 / v2;
                sim_sum += ((2.f * mu12 + C1c) * v1) / ((mu1s + mu2s + C1c) * v2);
            }
        }
    }

    // ---- Block reduction ----
#pragma unroll
    for (int off = 32; off > 0; off >>= 1) {
        cs_sum += __shfl_down(cs_sum, off, 64);
        sim_sum += __shfl_down(sim_sum, off, 64);
    }
    int wave = tid >> 6;
    if ((tid & 63) == 0) {
        red[wave * 2 + 0] = sim_sum;
        red[wave * 2 + 1] = cs_sum;
    }
    __syncthreads();
    if (tid == 0) {
        float s = red[0] + red[2] + red[4] + red[6];
        float cc = red[1] + red[3] + red[5] + red[7];
        atomicAdd(&acc[(lvl * NCH + c) * 2 + 0], s);
        atomicAdd(&acc[(lvl * NCH + c) * 2 + 1], cc);
    }
}

__global__ void finalize_k(const float* __restrict__ acc, float* __restrict__ out) {
    if (threadIdx.x != 0) return;
    const double w[5] = {0.0448, 0.2856, 0.3001, 0.2363, 0.1333};
    const double counts[5] = {1014.0 * 1014.0, 502.0 * 502.0, 246.0 * 246.0,
                              118.0 * 118.0, 54.0 * 54.0};
    double total = 0.0;
    for (int c = 0; c < NCH; ++c) {
        double pc = 1.0;
        for (int l = 0; l < 4; ++l) {
            double mcs = (double)acc[(l * NCH + c) * 2 + 1] / counts[l];
            pc *= pow(mcs, w[l]);
        }
        double ms4 = (double)acc[(4 * NCH + c) * 2 + 0] / counts[4];
        double p2 = pow(ms4, w[4]);
        pc *= (p2 * p2) * (p2 * p2);  // pow2[-1] appears in all 4 product terms
        total += pc;
    }
    *out = (float)(1.0 - total);
}

extern "C" void kernel_launch(void* const* d_in, const int* in_sizes, int n_in,
                              void* d_out, int out_size, void* d_ws, size_t ws_size,
                              hipStream_t stream) {
    const float* P0 = (const float*)d_in[0];
    const float* T0 = (const float*)d_in[1];
    float* out = (float*)d_out;
    float* acc = (float*)d_ws;  // 100 used, 128 reserved

    const size_t n1 = (size_t)NCH * 512 * 512;
    const size_t n2 = (size_t)NCH * 256 * 256;
    const size_t n3 = (size_t)NCH * 128 * 128;
    const size_t n4 = (size_t)NCH * 64 * 64;
    float* p1 = acc + 128;
    float* t1 = p1 + n1;
    float* p2 = t1 + n1;
    float* t2 = p2 + n2;
    float* p3 = t2 + n2;
    float* t3 = p3 + n3;
    float* p4 = t3 + n3;
    float* t4 = p4 + n4;

    zero_acc<<<1, 128, 0, stream>>>(acc);

    pool2x2<<<(int)((n1 + 255) / 256), 256, 0, stream>>>(P0, T0, p1, t1, 1024);
    pool2x2<<<(int)((n2 + 255) / 256), 256, 0, stream>>>(p1, t1, p2, t2, 512);
    pool2x2<<<(int)((n3 + 255) / 256), 256, 0, stream>>>(p2, t2, p3, t3, 256);
    pool2x2<<<(int)((n4 + 255) / 256), 256, 0, stream>>>(p3, t3, p4, t4, 128);

    Ptrs ptrs;
    ptrs.p[0] = P0; ptrs.t[0] = T0;
    ptrs.p[1] = p1; ptrs.t[1] = t1;
    ptrs.p[2] = p2; ptrs.t[2] = t2;
    ptrs.p[3] = p3; ptrs.t[3] = t3;
    ptrs.p[4] = p4; ptrs.t[4] = t4;

    ssim_all<<<dim3(1364, NCH, 1), 256, 0, stream>>>(ptrs, acc);

    finalize_k<<<1, 64, 0, stream>>>(acc, out);
}

// Round 4
// 267.180 us; speedup vs baseline: 1.9387x; 1.4858x over previous
//
#include <hip/hip_runtime.h>
#include <cstddef>

#define WIN 11
#define HALO 10
#define NCH 10

// Normalized 1D Gaussian, sigma=1.5 (constexpr: unrolled taps fold to immediates)
constexpr float Gc[WIN] = {
    0.00102838f, 0.00759876f, 0.03600077f, 0.10936069f, 0.21300554f,
    0.26601173f, 0.21300554f, 0.10936069f, 0.03600077f, 0.00759876f,
    0.00102838f};

constexpr int TX = 32;
constexpr int TY = 32;
constexpr int IN_H = TY + HALO;     // 42 h-rows per tile
constexpr int HPITCH = 33;          // write bank=(r+x)%32 -> spread, reads clean
constexpr int HSZ = IN_H * HPITCH;  // 1386

struct Ptrs {
    const float* p[5];
    const float* t[5];
};

// ---- One-shot pyramid: 64x64 level-0 tile -> levels 1..4, plus acc zeroing ----
__global__ __launch_bounds__(256) void pool_all(
    const float* __restrict__ P0, const float* __restrict__ T0,
    float* __restrict__ p1, float* __restrict__ t1,
    float* __restrict__ p2, float* __restrict__ t2,
    float* __restrict__ p3, float* __restrict__ t3,
    float* __restrict__ p4, float* __restrict__ t4,
    float* __restrict__ acc) {
    __shared__ float sp2[256], st2[256], sp3[64], st3[64];
    const int tid = threadIdx.x;
    if (blockIdx.x == 0 && tid < 128) acc[tid] = 0.f;

    const int b = blockIdx.x;           // 2560 = 10ch x 16 x 16
    const int bx = b & 15, by = (b >> 4) & 15, ch = b >> 8;
    const int tx = tid & 15, ty = tid >> 4;

    const size_t rbase =
        ((size_t)ch * 1024 + by * 64 + ty * 4) * 1024 + bx * 64 + tx * 4;
    float4 pr[4], tr[4];
#pragma unroll
    for (int r2 = 0; r2 < 4; ++r2) {
        pr[r2] = *(const float4*)(P0 + rbase + (size_t)r2 * 1024);
        tr[r2] = *(const float4*)(T0 + rbase + (size_t)r2 * 1024);
    }
    // level 1 (2x2 outputs per thread)
    float p1a = 0.25f * ((pr[0].x + pr[0].y) + (pr[1].x + pr[1].y));
    float p1b = 0.25f * ((pr[0].z + pr[0].w) + (pr[1].z + pr[1].w));
    float p1c = 0.25f * ((pr[2].x + pr[2].y) + (pr[3].x + pr[3].y));
    float p1d = 0.25f * ((pr[2].z + pr[2].w) + (pr[3].z + pr[3].w));
    float t1a = 0.25f * ((tr[0].x + tr[0].y) + (tr[1].x + tr[1].y));
    float t1b = 0.25f * ((tr[0].z + tr[0].w) + (tr[1].z + tr[1].w));
    float t1c = 0.25f * ((tr[2].x + tr[2].y) + (tr[3].x + tr[3].y));
    float t1d = 0.25f * ((tr[2].z + tr[2].w) + (tr[3].z + tr[3].w));
    size_t o1 = ((size_t)ch * 512 + by * 32 + ty * 2) * 512 + bx * 32 + tx * 2;
    *(float2*)(p1 + o1) = make_float2(p1a, p1b);
    *(float2*)(p1 + o1 + 512) = make_float2(p1c, p1d);
    *(float2*)(t1 + o1) = make_float2(t1a, t1b);
    *(float2*)(t1 + o1 + 512) = make_float2(t1c, t1d);
    // level 2 (1 output per thread)
    float p2v = 0.25f * ((p1a + p1b) + (p1c + p1d));
    float t2v = 0.25f * ((t1a + t1b) + (t1c + t1d));
    size_t o2 = ((size_t)ch * 256 + by * 16 + ty) * 256 + bx * 16 + tx;
    p2[o2] = p2v;
    t2[o2] = t2v;
    sp2[tid] = p2v;
    st2[tid] = t2v;
    __syncthreads();
    if (tid < 64) {  // level 3: 8x8
        int x3 = tid & 7, y3 = tid >> 3;
        int i0 = (2 * y3) * 16 + 2 * x3;
        float p3v = 0.25f * ((sp2[i0] + sp2[i0 + 1]) + (sp2[i0 + 16] + sp2[i0 + 17]));
        float t3v = 0.25f * ((st2[i0] + st2[i0 + 1]) + (st2[i0 + 16] + st2[i0 + 17]));
        size_t o3 = ((size_t)ch * 128 + by * 8 + y3) * 128 + bx * 8 + x3;
        p3[o3] = p3v;
        t3[o3] = t3v;
        sp3[tid] = p3v;
        st3[tid] = t3v;
    }
    __syncthreads();
    if (tid < 16) {  // level 4: 4x4
        int x4 = tid & 3, y4 = tid >> 2;
        int i0 = (2 * y4) * 8 + 2 * x4;
        float p4v = 0.25f * ((sp3[i0] + sp3[i0 + 1]) + (sp3[i0 + 8] + sp3[i0 + 9]));
        float t4v = 0.25f * ((st3[i0] + st3[i0 + 1]) + (st3[i0 + 8] + st3[i0 + 9]));
        size_t o4 = ((size_t)ch * 64 + by * 4 + y4) * 64 + bx * 4 + x4;
        p4[o4] = p4v;
        t4[o4] = t4v;
    }
}

// All 5 levels, TWO adjacent x-tiles per block (prefetch pipeline).
// Per-level pair counts: 512/128/32/8/2 -> 682. blockIdx.y = channel.
__global__ __launch_bounds__(256, 4) void ssim_all(Ptrs ptrs,
                                                   float* __restrict__ acc) {
    __shared__ float hbuf[5 * HSZ];  // 27.7 KB -> 5 blocks/CU
    __shared__ float red[8];

    const int bx = blockIdx.x;
    int lvl, base;
    if (bx < 512)      { lvl = 0; base = 0; }
    else if (bx < 640) { lvl = 1; base = 512; }
    else if (bx < 672) { lvl = 2; base = 640; }
    else if (bx < 680) { lvl = 3; base = 672; }
    else               { lvl = 4; base = 680; }
    const int local = bx - base;
    const int pw = 16 >> lvl;  // pairs per row
    const int pxb = local & (pw - 1);
    const int tyb = local >> (4 - lvl);
    const int H = 1024 >> lvl;
    const int Hout = H - HALO;
    const int oxp = pxb * 64;  // pair x-origin (two 32-wide tiles)
    const int oy0 = tyb * TY;
    const int c = blockIdx.y;
    const float* Pc = ptrs.p[lvl] + (size_t)c * H * H;
    const float* Tc = ptrs.t[lvl] + (size_t)c * H * H;
    const int tid = threadIdx.x;
    const int r = tid / 6;
    const int seg = tid - r * 6;
    const int x0s = seg * 6;
    const int gy = oy0 + r;

    // ---- Prefetch BOTH tiles' windows up front (tile1's loads stay in
    //      flight across tile0's compute: vmcnt(16), not vmcnt(0)) ----
    float wp[2][16], wt[2][16];
#pragma unroll
    for (int s = 0; s < 2; ++s) {
        if (tid < 252) {
            const int gxb = oxp + s * TX + x0s;
            const float* Pr = Pc + (size_t)gy * H + gxb;
            const float* Tr = Tc + (size_t)gy * H + gxb;
            if (gy < H && gxb + 16 <= H) {  // fast path
#pragma unroll
                for (int j = 0; j < 8; ++j) {
                    float2 pv = *(const float2*)(Pr + 2 * j);
                    float2 tv = *(const float2*)(Tr + 2 * j);
                    wp[s][2 * j] = pv.x; wp[s][2 * j + 1] = pv.y;
                    wt[s][2 * j] = tv.x; wt[s][2 * j + 1] = tv.y;
                }
            } else {
#pragma unroll
                for (int j = 0; j < 16; ++j) {
                    bool ok = (gy < H) && (gxb + j < H);
                    wp[s][j] = ok ? Pr[j] : 0.f;
                    wt[s][j] = ok ? Tr[j] : 0.f;
                }
            }
        }
    }

    float cs_sum = 0.f, sim_sum = 0.f;
#pragma unroll
    for (int s = 0; s < 2; ++s) {
        if (s == 1) __syncthreads();  // hbuf reuse guard

        // ---- Stage 1: horizontal conv from prefetched window ----
        if (tid < 252) {
            float a0[6] = {}, a1[6] = {}, a2[6] = {}, a3[6] = {}, a4[6] = {};
#pragma unroll
            for (int xi = 0; xi < 16; ++xi) {
                float pv = wp[s][xi], tv = wt[s][xi];
                float pp = pv * pv, tt = tv * tv, pt = pv * tv;
#pragma unroll
                for (int o = 0; o < 6; ++o) {
                    int k = xi - o;
                    if (k >= 0 && k <= 10) {
                        float g = Gc[k];
                        a0[o] = fmaf(g, pv, a0[o]);
                        a1[o] = fmaf(g, tv, a1[o]);
                        a2[o] = fmaf(g, pp, a2[o]);
                        a3[o] = fmaf(g, tt, a3[o]);
                        a4[o] = fmaf(g, pt, a4[o]);
                    }
                }
            }
#pragma unroll
            for (int o = 0; o < 6; ++o) {
                int x = x0s + o;
                if (x < TX) {
                    int idx = r * HPITCH + x;
                    hbuf[0 * HSZ + idx] = a0[o];
                    hbuf[1 * HSZ + idx] = a1[o];
                    hbuf[2 * HSZ + idx] = a2[o];
                    hbuf[3 * HSZ + idx] = a3[o];
                    hbuf[4 * HSZ + idx] = a4[o];
                }
            }
        }
        __syncthreads();

        // ---- Stage 2: vertical conv + SSIM, 4 outputs/thread ----
        {
            const int txl = tid & 31;
            const int y0 = (tid >> 5) * 4;
            float m1[4] = {}, m2[4] = {}, q11[4] = {}, q22[4] = {}, q12[4] = {};
#pragma unroll
            for (int yr = 0; yr < 14; ++yr) {
                int row = (y0 + yr) * HPITCH + txl;
                float h0 = hbuf[0 * HSZ + row];
                float h1 = hbuf[1 * HSZ + row];
                float h2 = hbuf[2 * HSZ + row];
                float h3 = hbuf[3 * HSZ + row];
                float h4 = hbuf[4 * HSZ + row];
#pragma unroll
                for (int o = 0; o < 4; ++o) {
                    int k = yr - o;
                    if (k >= 0 && k <= 10) {
                        float gw = Gc[k];
                        m1[o] = fmaf(gw, h0, m1[o]);
                        m2[o] = fmaf(gw, h1, m2[o]);
                        q11[o] = fmaf(gw, h2, q11[o]);
                        q22[o] = fmaf(gw, h3, q22[o]);
                        q12[o] = fmaf(gw, h4, q12[o]);
                    }
                }
            }
            const float C1c = 1.0e-4f, C2c = 9.0e-4f;
            const int ox = oxp + s * TX + txl;
#pragma unroll
            for (int o = 0; o < 4; ++o) {
                if (ox < Hout && oy0 + y0 + o < Hout) {
                    float mu1s = m1[o] * m1[o], mu2s = m2[o] * m2[o];
                    float mu12 = m1[o] * m2[o];
                    float sig1 = q11[o] - mu1s;
                    float sig2 = q22[o] - mu2s;
                    float sig12 = q12[o] - mu12;
                    float v1 = 2.f * sig12 + C2c;
                    float v2 = sig1 + sig2 + C2c;
                    cs_sum += v1 / v2;
                    sim_sum += ((2.f * mu12 + C1c) * v1) / ((mu1s + mu2s + C1c) * v2);
                }
            }
        }
    }

    // ---- Block reduction (once per pair) ----
#pragma unroll
    for (int off = 32; off > 0; off >>= 1) {
        cs_sum += __shfl_down(cs_sum, off, 64);
        sim_sum += __shfl_down(sim_sum, off, 64);
    }
    int wave = tid >> 6;
    if ((tid & 63) == 0) {
        red[wave * 2 + 0] = sim_sum;
        red[wave * 2 + 1] = cs_sum;
    }
    __syncthreads();
    if (tid == 0) {
        float s = red[0] + red[2] + red[4] + red[6];
        float cc = red[1] + red[3] + red[5] + red[7];
        atomicAdd(&acc[(lvl * NCH + c) * 2 + 0], s);
        atomicAdd(&acc[(lvl * NCH + c) * 2 + 1], cc);
    }
}

__global__ void finalize_k(const float* __restrict__ acc, float* __restrict__ out) {
    if (threadIdx.x != 0) return;
    const double w[5] = {0.0448, 0.2856, 0.3001, 0.2363, 0.1333};
    const double counts[5] = {1014.0 * 1014.0, 502.0 * 502.0, 246.0 * 246.0,
                              118.0 * 118.0, 54.0 * 54.0};
    double total = 0.0;
    for (int c = 0; c < NCH; ++c) {
        double pc = 1.0;
        for (int l = 0; l < 4; ++l) {
            double mcs = (double)acc[(l * NCH + c) * 2 + 1] / counts[l];
            pc *= pow(mcs, w[l]);
        }
        double ms4 = (double)acc[(4 * NCH + c) * 2 + 0] / counts[4];
        double p2 = pow(ms4, w[4]);
        pc *= (p2 * p2) * (p2 * p2);  // pow2[-1] appears in all 4 product terms
        total += pc;
    }
    *out = (float)(1.0 - total);
}

extern "C" void kernel_launch(void* const* d_in, const int* in_sizes, int n_in,
                              void* d_out, int out_size, void* d_ws, size_t ws_size,
                              hipStream_t stream) {
    const float* P0 = (const float*)d_in[0];
    const float* T0 = (const float*)d_in[1];
    float* out = (float*)d_out;
    float* acc = (float*)d_ws;  // 100 used, 128 reserved

    const size_t n1 = (size_t)NCH * 512 * 512;
    const size_t n2 = (size_t)NCH * 256 * 256;
    const size_t n3 = (size_t)NCH * 128 * 128;
    const size_t n4 = (size_t)NCH * 64 * 64;
    float* p1 = acc + 128;
    float* t1 = p1 + n1;
    float* p2 = t1 + n1;
    float* t2 = p2 + n2;
    float* p3 = t2 + n2;
    float* t3 = p3 + n3;
    float* p4 = t3 + n3;
    float* t4 = p4 + n4;

    pool_all<<<2560, 256, 0, stream>>>(P0, T0, p1, t1, p2, t2, p3, t3, p4, t4, acc);

    Ptrs ptrs;
    ptrs.p[0] = P0; ptrs.t[0] = T0;
    ptrs.p[1] = p1; ptrs.t[1] = t1;
    ptrs.p[2] = p2; ptrs.t[2] = t2;
    ptrs.p[3] = p3; ptrs.t[3] = t3;
    ptrs.p[4] = p4; ptrs.t[4] = t4;

    ssim_all<<<dim3(682, NCH, 1), 256, 0, stream>>>(ptrs, acc);

    finalize_k<<<1, 64, 0, stream>>>(acc, out);
}

// Round 5
// 265.188 us; speedup vs baseline: 1.9532x; 1.0075x over previous
//
#include <hip/hip_runtime.h>
#include <cstddef>

#define WIN 11
#define HALO 10
#define NCH 10

typedef float v2f __attribute__((ext_vector_type(2)));

// Normalized 1D Gaussian, sigma=1.5 (constexpr: unrolled taps fold to immediates)
constexpr float Gc[WIN] = {
    0.00102838f, 0.00759876f, 0.03600077f, 0.10936069f, 0.21300554f,
    0.26601173f, 0.21300554f, 0.10936069f, 0.03600077f, 0.00759876f,
    0.00102838f};

constexpr int TX = 32;
constexpr int TY = 32;
constexpr int IN_H = TY + HALO;     // 42 h-rows per tile
constexpr int HPITCH = 33;          // write bank spread; stage-2 reads clean
constexpr int HSZ = IN_H * HPITCH;  // 1386

struct Ptrs {
    const float* p[5];
    const float* t[5];
};

// ---- One-shot pyramid: 64x64 level-0 tile -> levels 1..4, plus acc zeroing ----
__global__ __launch_bounds__(256) void pool_all(
    const float* __restrict__ P0, const float* __restrict__ T0,
    float* __restrict__ p1, float* __restrict__ t1,
    float* __restrict__ p2, float* __restrict__ t2,
    float* __restrict__ p3, float* __restrict__ t3,
    float* __restrict__ p4, float* __restrict__ t4,
    float* __restrict__ acc) {
    __shared__ float sp2[256], st2[256], sp3[64], st3[64];
    const int tid = threadIdx.x;
    if (blockIdx.x == 0 && tid < 128) acc[tid] = 0.f;

    const int b = blockIdx.x;  // 2560 = 10ch x 16 x 16
    const int bx = b & 15, by = (b >> 4) & 15, ch = b >> 8;
    const int tx = tid & 15, ty = tid >> 4;

    const size_t rbase =
        ((size_t)ch * 1024 + by * 64 + ty * 4) * 1024 + bx * 64 + tx * 4;
    float4 pr[4], tr[4];
#pragma unroll
    for (int r2 = 0; r2 < 4; ++r2) {
        pr[r2] = *(const float4*)(P0 + rbase + (size_t)r2 * 1024);
        tr[r2] = *(const float4*)(T0 + rbase + (size_t)r2 * 1024);
    }
    float p1a = 0.25f * ((pr[0].x + pr[0].y) + (pr[1].x + pr[1].y));
    float p1b = 0.25f * ((pr[0].z + pr[0].w) + (pr[1].z + pr[1].w));
    float p1c = 0.25f * ((pr[2].x + pr[2].y) + (pr[3].x + pr[3].y));
    float p1d = 0.25f * ((pr[2].z + pr[2].w) + (pr[3].z + pr[3].w));
    float t1a = 0.25f * ((tr[0].x + tr[0].y) + (tr[1].x + tr[1].y));
    float t1b = 0.25f * ((tr[0].z + tr[0].w) + (tr[1].z + tr[1].w));
    float t1c = 0.25f * ((tr[2].x + tr[2].y) + (tr[3].x + tr[3].y));
    float t1d = 0.25f * ((tr[2].z + tr[2].w) + (tr[3].z + tr[3].w));
    size_t o1 = ((size_t)ch * 512 + by * 32 + ty * 2) * 512 + bx * 32 + tx * 2;
    *(float2*)(p1 + o1) = make_float2(p1a, p1b);
    *(float2*)(p1 + o1 + 512) = make_float2(p1c, p1d);
    *(float2*)(t1 + o1) = make_float2(t1a, t1b);
    *(float2*)(t1 + o1 + 512) = make_float2(t1c, t1d);
    float p2v = 0.25f * ((p1a + p1b) + (p1c + p1d));
    float t2v = 0.25f * ((t1a + t1b) + (t1c + t1d));
    size_t o2 = ((size_t)ch * 256 + by * 16 + ty) * 256 + bx * 16 + tx;
    p2[o2] = p2v;
    t2[o2] = t2v;
    sp2[tid] = p2v;
    st2[tid] = t2v;
    __syncthreads();
    if (tid < 64) {
        int x3 = tid & 7, y3 = tid >> 3;
        int i0 = (2 * y3) * 16 + 2 * x3;
        float p3v = 0.25f * ((sp2[i0] + sp2[i0 + 1]) + (sp2[i0 + 16] + sp2[i0 + 17]));
        float t3v = 0.25f * ((st2[i0] + st2[i0 + 1]) + (st2[i0 + 16] + st2[i0 + 17]));
        size_t o3 = ((size_t)ch * 128 + by * 8 + y3) * 128 + bx * 8 + x3;
        p3[o3] = p3v;
        t3[o3] = t3v;
        sp3[tid] = p3v;
        st3[tid] = t3v;
    }
    __syncthreads();
    if (tid < 16) {
        int x4 = tid & 3, y4 = tid >> 2;
        int i0 = (2 * y4) * 8 + 2 * x4;
        float p4v = 0.25f * ((sp3[i0] + sp3[i0 + 1]) + (sp3[i0 + 8] + sp3[i0 + 9]));
        float t4v = 0.25f * ((st3[i0] + st3[i0 + 1]) + (st3[i0 + 8] + st3[i0 + 9]));
        size_t o4 = ((size_t)ch * 64 + by * 4 + y4) * 64 + bx * 4 + x4;
        p4[o4] = p4v;
        t4[o4] = t4v;
    }
}

// All 5 levels, two adjacent x-tiles per block, packed-fp32 conv math.
// Per-level pair counts: 512/128/32/8/2 -> 682. blockIdx.y = channel.
__global__ __launch_bounds__(256, 5) void ssim_all(Ptrs ptrs,
                                                   float* __restrict__ acc) {
    __shared__ v2f h01[HSZ];   // (conv(p), conv(t))      11088 B
    __shared__ v2f h23[HSZ];   // (conv(p^2), conv(t^2))  11088 B
    __shared__ float h4s[HSZ]; // conv(p*t)                5544 B
    __shared__ float red[8];

    const int bxi = blockIdx.x;
    int lvl, base;
    if (bxi < 512)      { lvl = 0; base = 0; }
    else if (bxi < 640) { lvl = 1; base = 512; }
    else if (bxi < 672) { lvl = 2; base = 640; }
    else if (bxi < 680) { lvl = 3; base = 672; }
    else                { lvl = 4; base = 680; }
    const int local = bxi - base;
    const int pw_ = 16 >> lvl;  // pairs per row
    const int pxb = local & (pw_ - 1);
    const int tyb = local >> (4 - lvl);
    const int H = 1024 >> lvl;
    const int Hout = H - HALO;
    const int oxp = pxb * 64;
    const int oy0 = tyb * TY;
    const int c = blockIdx.y;
    const float* Pc = ptrs.p[lvl] + (size_t)c * H * H;
    const float* Tc = ptrs.t[lvl] + (size_t)c * H * H;
    const int tid = threadIdx.x;
    const int r = tid / 6;
    const int seg = tid - r * 6;
    const int x0s = seg * 6;
    const int gy = oy0 + r;

    float cs_sum = 0.f, sim_sum = 0.f;
#pragma unroll
    for (int s = 0; s < 2; ++s) {
        if (s == 1) __syncthreads();  // hbuf reuse guard

        // ---- Stage 1: horizontal conv from global, packed accumulators ----
        if (tid < 252) {
            const int gxb = oxp + s * TX + x0s;
            const float* Pr = Pc + (size_t)gy * H + gxb;
            const float* Tr = Tc + (size_t)gy * H + gxb;
            v2f win[16];  // (p, t)
            if (gy < H && gxb + 16 <= H) {  // fast path
#pragma unroll
                for (int j = 0; j < 8; ++j) {
                    float2 pv = *(const float2*)(Pr + 2 * j);
                    float2 tv = *(const float2*)(Tr + 2 * j);
                    win[2 * j] = (v2f){pv.x, tv.x};
                    win[2 * j + 1] = (v2f){pv.y, tv.y};
                }
            } else {
#pragma unroll
                for (int j = 0; j < 16; ++j) {
                    bool ok = (gy < H) && (gxb + j < H);
                    win[j] = (v2f){ok ? Pr[j] : 0.f, ok ? Tr[j] : 0.f};
                }
            }
            v2f a01[6] = {}, a23[6] = {};
            float a4[6] = {};
#pragma unroll
            for (int xi = 0; xi < 16; ++xi) {
                v2f x01 = win[xi];
                v2f x23 = x01 * x01;          // v_pk_mul_f32
                float x4 = x01.x * x01.y;
#pragma unroll
                for (int o = 0; o < 6; ++o) {
                    int k = xi - o;
                    if (k >= 0 && k <= 10) {
                        float g = Gc[k];
                        a01[o] = a01[o] + g * x01;  // v_pk_fma_f32
                        a23[o] = a23[o] + g * x23;  // v_pk_fma_f32
                        a4[o] = fmaf(g, x4, a4[o]);
                    }
                }
            }
#pragma unroll
            for (int o = 0; o < 6; ++o) {
                int x = x0s + o;
                if (x < TX) {
                    int idx = r * HPITCH + x;
                    h01[idx] = a01[o];  // ds_write_b64
                    h23[idx] = a23[o];
                    h4s[idx] = a4[o];
                }
            }
        }
        __syncthreads();

        // ---- Stage 2: vertical conv + SSIM, packed, 4 outputs/thread ----
        {
            const int txl = tid & 31;
            const int y0 = (tid >> 5) * 4;
            v2f m12[4] = {}, q12v[4] = {};
            float sA[4] = {};
#pragma unroll
            for (int yr = 0; yr < 14; ++yr) {
                int row = (y0 + yr) * HPITCH + txl;
                v2f v01 = h01[row];   // ds_read_b64
                v2f v23 = h23[row];   // ds_read_b64
                float v4 = h4s[row];  // ds_read_b32
#pragma unroll
                for (int o = 0; o < 4; ++o) {
                    int k = yr - o;
                    if (k >= 0 && k <= 10) {
                        float gw = Gc[k];
                        m12[o] = m12[o] + gw * v01;
                        q12v[o] = q12v[o] + gw * v23;
                        sA[o] = fmaf(gw, v4, sA[o]);
                    }
                }
            }
            const float C1c = 1.0e-4f, C2c = 9.0e-4f;
            const int ox = oxp + s * TX + txl;
#pragma unroll
            for (int o = 0; o < 4; ++o) {
                if (ox < Hout && oy0 + y0 + o < Hout) {
                    float mu1 = m12[o].x, mu2 = m12[o].y;
                    float mu1s = mu1 * mu1, mu2s = mu2 * mu2, mu12 = mu1 * mu2;
                    float sig1 = q12v[o].x - mu1s;
                    float sig2 = q12v[o].y - mu2s;
                    float sig12 = sA[o] - mu12;
                    float v1 = 2.f * sig12 + C2c;
                    float v2 = sig1 + sig2 + C2c;
                    float den2 = mu1s + mu2s + C1c;
                    float num2 = 2.f * mu12 + C1c;
                    float inv = 1.f / (v2 * den2);  // one divide for both terms
                    cs_sum = fmaf(v1 * den2, inv, cs_sum);
                    sim_sum = fmaf(num2 * v1, inv, sim_sum);
                }
            }
        }
    }

    // ---- Block reduction (once per pair) ----
#pragma unroll
    for (int off = 32; off > 0; off >>= 1) {
        cs_sum += __shfl_down(cs_sum, off, 64);
        sim_sum += __shfl_down(sim_sum, off, 64);
    }
    int wave = tid >> 6;
    if ((tid & 63) == 0) {
        red[wave * 2 + 0] = sim_sum;
        red[wave * 2 + 1] = cs_sum;
    }
    __syncthreads();
    if (tid == 0) {
        float s = red[0] + red[2] + red[4] + red[6];
        float cc = red[1] + red[3] + red[5] + red[7];
        atomicAdd(&acc[(lvl * NCH + c) * 2 + 0], s);
        atomicAdd(&acc[(lvl * NCH + c) * 2 + 1], cc);
    }
}

__global__ void finalize_k(const float* __restrict__ acc, float* __restrict__ out) {
    if (threadIdx.x != 0) return;
    const double w[5] = {0.0448, 0.2856, 0.3001, 0.2363, 0.1333};
    const double counts[5] = {1014.0 * 1014.0, 502.0 * 502.0, 246.0 * 246.0,
                              118.0 * 118.0, 54.0 * 54.0};
    double total = 0.0;
    for (int c = 0; c < NCH; ++c) {
        double pc = 1.0;
        for (int l = 0; l < 4; ++l) {
            double mcs = (double)acc[(l * NCH + c) * 2 + 1] / counts[l];
            pc *= pow(mcs, w[l]);
        }
        double ms4 = (double)acc[(4 * NCH + c) * 2 + 0] / counts[4];
        double p2 = pow(ms4, w[4]);
        pc *= (p2 * p2) * (p2 * p2);  // pow2[-1] appears in all 4 product terms
        total += pc;
    }
    *out = (float)(1.0 - total);
}

extern "C" void kernel_launch(void* const* d_in, const int* in_sizes, int n_in,
                              void* d_out, int out_size, void* d_ws, size_t ws_size,
                              hipStream_t stream) {
    const float* P0 = (const float*)d_in[0];
    const float* T0 = (const float*)d_in[1];
    float* out = (float*)d_out;
    float* acc = (float*)d_ws;  // 100 used, 128 reserved

    const size_t n1 = (size_t)NCH * 512 * 512;
    const size_t n2 = (size_t)NCH * 256 * 256;
    const size_t n3 = (size_t)NCH * 128 * 128;
    const size_t n4 = (size_t)NCH * 64 * 64;
    float* p1 = acc + 128;
    float* t1 = p1 + n1;
    float* p2 = t1 + n1;
    float* t2 = p2 + n2;
    float* p3 = t2 + n2;
    float* t3 = p3 + n3;
    float* p4 = t3 + n3;
    float* t4 = p4 + n4;

    pool_all<<<2560, 256, 0, stream>>>(P0, T0, p1, t1, p2, t2, p3, t3, p4, t4, acc);

    Ptrs ptrs;
    ptrs.p[0] = P0; ptrs.t[0] = T0;
    ptrs.p[1] = p1; ptrs.t[1] = t1;
    ptrs.p[2] = p2; ptrs.t[2] = t2;
    ptrs.p[3] = p3; ptrs.t[3] = t3;
    ptrs.p[4] = p4; ptrs.t[4] = t4;

    ssim_all<<<dim3(682, NCH, 1), 256, 0, stream>>>(ptrs, acc);

    finalize_k<<<1, 64, 0, stream>>>(acc, out);
}